// Round 4
// baseline (301.155 us; speedup 1.0000x reference)
//
#include <hip/hip_runtime.h>

// RoiPooling via integral image, 3-pass:
//  P1 rowScanCF: fm (C,H,W) -> S1[c][y][x] = cumsum_x(fm), channel-first, dense.
//  P2 colScanT : S1 -> S[y][x][c] (channel-last, with zero borders), column scan
//                split into 16 local y-chunks of 16 rows (no cross-chunk carry).
//  offsetK     : OP[k][x][c] = prefix sums of chunk totals (8.9 MB, L2-resident).
//  gatherK     : corner value = S_local + OP[chunk(y)]; 4-corner difference.
//
// ws layout (floats):
//   S  @ 0          size 257*257*512 = 33,817,088   [y][x][c]
//   S1 @ 33817088   size 512*256*256 = 33,554,432   [c][y][x]
//   OP @ 67371520   size  17*257*512 =  2,236,416   [k][x][c]
// total 278.4 MB <= ws (512 MB+).

#define CHN 512
#define HD  256
#define WD  256
#define SP  257
#define YCH 16
#define S1_OFF 33817088UL
#define OP_OFF 67371520UL

// ---------------- P1: row prefix scan, channel-first, dense ----------------
// One wave per (c,y) row: 64 lanes x float4 = 256 floats. No LDS.
__global__ __launch_bounds__(256) void rowScanCF(const float* __restrict__ fm,
                                                 float* __restrict__ S1) {
    const int t = threadIdx.x, lane = t & 63, wave = t >> 6;
    const int row = blockIdx.x * 4 + wave;        // 0 .. 131071  (c*256+y)
    const size_t base = (size_t)row * 256 + 4 * lane;
    const float4 v = *(const float4*)(fm + base);
    const float local = ((v.x + v.y) + v.z) + v.w;
    float s = local;
    #pragma unroll
    for (int d = 1; d < 64; d <<= 1) {
        float u = __shfl_up(s, d, 64);
        if (lane >= d) s += u;
    }
    const float e = s - local;                    // exclusive lane prefix
    float4 p;
    p.x = e   + v.x;
    p.y = p.x + v.y;
    p.z = p.y + v.z;
    p.w = p.z + v.w;
    *(float4*)(S1 + base) = p;
}

// ---------------- P2: chunked column scan + transpose to channel-last ------
// Block: 256 thr, tile = 32 x  X  128 c, one y-chunk of 16 rows.
// Grid: 8 xt * 4 ct * 16 k = 512 blocks (2 blocks/CU).
// Per y: coalesced 128B reads from S1, fp64 acc (4x4 per thread), register
// transpose -> LDS[32][132] -> dense 512B-per-x channel-last stores.
__global__ __launch_bounds__(256) void colScanT(const float* __restrict__ S1,
                                                float* __restrict__ S) {
    __shared__ float T[32][132];
    const int t = threadIdx.x, lane = t & 63, wave = t >> 6;
    const int bid = blockIdx.x;
    const int xt = bid & 7, ct = (bid >> 3) & 3, k = bid >> 5;
    const int x0 = xt * 32, c0 = ct * 128;

    // load-phase mapping: lane -> x-quad q (8), c-row rb (8)
    const int q  = lane & 7;
    const int rb = lane >> 3;
    const int cl = wave * 32 + rb * 4;            // c_local base (j = 0..3)
    const int xl = 4 * q;                         // x_local base (i = 0..3)

    // store-phase mapping: t -> c-quad cq (32), x base xs (8)
    const int cq = t & 31;
    const int xs = t >> 5;

    const float4 z4 = make_float4(0.f, 0.f, 0.f, 0.f);
    if (k == 0) {                                 // y=0 border row
        #pragma unroll
        for (int m = 0; m < 4; ++m)
            *(float4*)(S + (size_t)(x0 + xs + 8 * m + 1) * CHN + c0 + 4 * cq) = z4;
        if (xt == 0 && t < 32)
            *(float4*)(S + (size_t)0 * CHN + c0 + 4 * t) = z4;  // corner (0,0)
    }

    double acc[4][4];
    #pragma unroll
    for (int j = 0; j < 4; ++j)
        #pragma unroll
        for (int i = 0; i < 4; ++i) acc[j][i] = 0.0;

    const int r0 = k * YCH;                       // S1 row base
    float4 cur[4], nxt[4];
    #pragma unroll
    for (int j = 0; j < 4; ++j)
        cur[j] = *(const float4*)(S1 + ((size_t)(c0 + cl + j) << 16)
                                     + (size_t)r0 * 256 + x0 + xl);

    for (int yy = 0; yy < YCH; ++yy) {
        if (yy < YCH - 1) {
            #pragma unroll
            for (int j = 0; j < 4; ++j)
                nxt[j] = *(const float4*)(S1 + ((size_t)(c0 + cl + j) << 16)
                                             + (size_t)(r0 + yy + 1) * 256 + x0 + xl);
        }
        #pragma unroll
        for (int j = 0; j < 4; ++j) {
            acc[j][0] += (double)cur[j].x;
            acc[j][1] += (double)cur[j].y;
            acc[j][2] += (double)cur[j].z;
            acc[j][3] += (double)cur[j].w;
        }
        // register transpose: for each of my 4 x, the 4 j's are consecutive c
        #pragma unroll
        for (int i = 0; i < 4; ++i) {
            float4 w;
            w.x = (float)acc[0][i];
            w.y = (float)acc[1][i];
            w.z = (float)acc[2][i];
            w.w = (float)acc[3][i];
            *(float4*)&T[xl + i][cl] = w;
        }
        __syncthreads();
        const int yS = r0 + yy + 1;               // S array row (1..256)
        #pragma unroll
        for (int m = 0; m < 4; ++m) {
            const int x_l = xs + 8 * m;
            const float4 o = *(const float4*)&T[x_l][4 * cq];
            *(float4*)(S + ((size_t)yS * SP + (x0 + x_l + 1)) * CHN + c0 + 4 * cq) = o;
        }
        if (xt == 0 && t < 32)                    // x=0 border for this row
            *(float4*)(S + ((size_t)yS * SP) * CHN + c0 + 4 * t) = z4;
        __syncthreads();
        #pragma unroll
        for (int j = 0; j < 4; ++j) cur[j] = nxt[j];
    }
}

// ---------------- offsetK: prefix of chunk totals ---------------------------
// OP[k][x][c], k=0..16; OP[0]=OP[1]=0; OP[k>=2] = sum of chunk totals 0..k-2.
// Chunk j total = S[y=16(j+1)][x][c] (last local row of chunk j).
__global__ __launch_bounds__(256) void offsetK(const float* __restrict__ S,
                                               float* __restrict__ OP) {
    const int gid = blockIdx.x * 256 + threadIdx.x;   // 0 .. 131583 exactly
    const int c = gid & 511, x = gid >> 9;            // x 0..256
    OP[((size_t)0 * SP + x) * CHN + c] = 0.0f;
    OP[((size_t)1 * SP + x) * CHN + c] = 0.0f;
    double run = 0.0;
    #pragma unroll
    for (int j = 0; j < 15; ++j) {
        run += (double)S[((size_t)(16 * (j + 1)) * SP + x) * CHN + c];
        OP[((size_t)(j + 2) * SP + x) * CHN + c] = (float)run;
    }
}

// ---------------- gatherK: per-ROI 9-corner gather with offset add ---------
__global__ __launch_bounds__(256) void gatherK(const float* __restrict__ S,
                                              const float* __restrict__ OP,
                                              const float* __restrict__ roi,
                                              float* __restrict__ out,
                                              float* __restrict__ maskOut,
                                              int N) {
    const int n = blockIdx.x;
    const float xmin = roi[4 * n + 0];
    const float ymin = roi[4 * n + 1];
    const float xmax = roi[4 * n + 2];
    const float ymax = roi[4 * n + 3];

    // Replicate np fp32 op order exactly (no fma contraction).
    const float wsv = __fdiv_rn(__fsub_rn(xmax, xmin), 2.0f);
    const float hsv = __fdiv_rn(__fsub_rn(ymax, ymin), 2.0f);
    const float ax1 = __fadd_rn(xmin, wsv);
    const float ay1 = __fadd_rn(ymin, hsv);
    const float lim = (float)(WD - 1);

    int rx[3], ry[3];
    rx[0] = (int)fminf(fmaxf(rintf(xmin), 0.0f), lim);
    rx[1] = (int)fminf(fmaxf(rintf(ax1), 0.0f), lim);
    rx[2] = (int)fminf(fmaxf(rintf(__fadd_rn(ax1, wsv)), 0.0f), lim);
    ry[0] = (int)fminf(fmaxf(rintf(ymin), 0.0f), lim);
    ry[1] = (int)fminf(fmaxf(rintf(ay1), 0.0f), lim);
    ry[2] = (int)fminf(fmaxf(rintf(__fadd_rn(ay1, hsv)), 0.0f), lim);

    const int t = threadIdx.x;            // c-pair: channels 2t, 2t+1
    float2 g[3][3];
    #pragma unroll
    for (int j = 0; j < 3; ++j) {
        const int kk = (ry[j] + 15) >> 4; // chunk index row for OP
        #pragma unroll
        for (int i = 0; i < 3; ++i) {
            const float2 l = *(const float2*)(S  + ((size_t)ry[j] * SP + rx[i]) * CHN + 2 * t);
            const float2 o = *(const float2*)(OP + ((size_t)kk   * SP + rx[i]) * CHN + 2 * t);
            g[j][i] = make_float2(l.x + o.x, l.y + o.y);
        }
    }

    float m[4];
    #pragma unroll
    for (int p = 0; p < 4; ++p) {
        const int ix = p & 1, iy = p >> 1;
        const int cw = rx[ix + 1] - rx[ix];
        const int ch = ry[iy + 1] - ry[iy];
        const int maskv = (cw >= 1 && ch >= 1) ? 1 : 0;
        int areai = cw * ch; if (areai < 1) areai = 1;
        const float areaf = (float)areai;
        const float maskf = (float)maskv;
        m[p] = maskf;

        const float2 s11 = g[iy + 1][ix + 1];
        const float2 s01 = g[iy][ix + 1];
        const float2 s10 = g[iy + 1][ix];
        const float2 s00 = g[iy][ix];
        float2 o;  // reference order: ((S11 - S01) - S10) + S00, /area, *mask
        o.x = __fdiv_rn(((s11.x - s01.x) - s10.x) + s00.x, areaf) * maskf;
        o.y = __fdiv_rn(((s11.y - s01.y) - s10.y) + s00.y, areaf) * maskf;
        *(float2*)(out + ((size_t)p * N + n) * CHN + 2 * t) = o;
    }
    if (t < 4) maskOut[(size_t)t * N + n] = m[t];
}

// ---------------------------------------------------------------------------
extern "C" void kernel_launch(void* const* d_in, const int* in_sizes, int n_in,
                              void* d_out, int out_size, void* d_ws, size_t ws_size,
                              hipStream_t stream) {
    const float* fm  = (const float*)d_in[0];
    const float* roi = (const float*)d_in[1];
    // d_in[2] = patch_num (always 4 here); pe=2 hardcoded.

    const int N = in_sizes[1] / 4;     // 4096
    const int B = 4 * N;               // 16384

    float* S  = (float*)d_ws;
    float* S1 = (float*)d_ws + S1_OFF;
    float* OP = (float*)d_ws + OP_OFF;
    float* out     = (float*)d_out;
    float* maskOut = out + (size_t)B * CHN;

    rowScanCF<<<(CHN * HD) / 4, 256, 0, stream>>>(fm, S1);   // 32768 blocks
    colScanT<<<8 * 4 * 16, 256, 0, stream>>>(S1, S);         // 512 blocks
    offsetK<<<(SP * CHN) / 256, 256, 0, stream>>>(S, OP);    // 514 blocks
    gatherK<<<N, 256, 0, stream>>>(S, OP, roi, out, maskOut, N);
}

// Round 5
// 268.737 us; speedup vs baseline: 1.1206x; 1.1206x over previous
//
#include <hip/hip_runtime.h>

// RoiPooling via integral image, fused single-pass scan:
//  fusedScanK: fm (C,H,W) -> S[y][x][c] channel-last, where each y-chunk of 8
//              rows holds a LOCAL 2D integral (row-scan full-x, col-scan local
//              to chunk). Zero borders (y=0 row, x=0 col) written inline.
//  offsetK   : OP[k][x][c] = fp64 prefix over the 31 chunk totals (17 MB, L3).
//  gatherK   : corner value = S_local[ry][rx] + OP[chunk(ry)][rx]; 9-corner
//              per-ROI gather, 4-corner difference per patch.
//
// ws layout (floats):
//   S  @ 0          size 257*257*512 = 33,817,088  (135.3 MB)
//   OP @ 33817088   size  33*257*512 =  4,341,760  ( 17.4 MB)

#define CHN 512
#define HD  256
#define WD  256
#define SP  257
#define YC  8                 // rows per y-chunk
#define NK  32                // number of y-chunks
#define OP_OFF 33817088UL

// ---------------- fused scan: fm -> S (chunk-local integral) ---------------
// Block 256 thr; tile = 32 c x 256 x x 8 y. Grid (16 ct, 32 k) = 512 blocks.
// Per y: dense 1KB/wave loads, wave-shuffle row scan, LDS transpose (double
// buffered, ONE barrier per y), fp32 col-accumulate in store layout, dense
// 128B-segment channel-last stores.
__global__ __launch_bounds__(256) void fusedScanK(const float* __restrict__ fm,
                                                  float* __restrict__ S) {
    __shared__ float tile[2][32][260];   // 260 pad: 16B-aligned rows, 4-way read worst
    const int t = threadIdx.x, lane = t & 63, w = t >> 6;
    const int c0 = blockIdx.x * 32;
    const int k  = blockIdx.y;
    const int y0 = k * YC;

    const int cg = t & 7;                // store: 4-channel group
    const int x8 = t >> 3;               // store: x mod 32
    const float4 z4 = make_float4(0.f, 0.f, 0.f, 0.f);

    if (k == 0) {                        // y=0 border row, x=0..255
        #pragma unroll
        for (int it = 0; it < 8; ++it) {
            const int lin = it * 256 + t;
            const int cgg = lin & 7, x = lin >> 3;
            *(float4*)(S + (size_t)x * CHN + c0 + 4 * cgg) = z4;
        }
    }

    float4 cur[8], nxt[8];
    #pragma unroll
    for (int j = 0; j < 8; ++j)
        cur[j] = *(const float4*)(fm + ((size_t)(c0 + w * 8 + j) << 16)
                                     + (size_t)y0 * 256 + 4 * lane);

    float4 acc[8];
    #pragma unroll
    for (int m = 0; m < 8; ++m) acc[m] = z4;

    for (int y = 0; y < YC; ++y) {
        const int buf = y & 1;
        if (y < YC - 1) {                // prefetch next row-block (in flight
            #pragma unroll               //  across scan + store phases)
            for (int j = 0; j < 8; ++j)
                nxt[j] = *(const float4*)(fm + ((size_t)(c0 + w * 8 + j) << 16)
                                             + (size_t)(y0 + y + 1) * 256 + 4 * lane);
        }
        // row scan: wave w handles channels w*8..w*8+7, full 256-x per row
        #pragma unroll
        for (int j = 0; j < 8; ++j) {
            const float4 v = cur[j];
            const float local = ((v.x + v.y) + v.z) + v.w;
            float s = local;
            #pragma unroll
            for (int d = 1; d < 64; d <<= 1) {
                float u = __shfl_up(s, d, 64);
                if (lane >= d) s += u;
            }
            const float e = s - local;   // exclusive lane prefix
            float4 p;
            p.x = e   + v.x;
            p.y = p.x + v.y;
            p.z = p.y + v.z;
            p.w = p.z + v.w;
            *(float4*)&tile[buf][w * 8 + j][4 * lane] = p;
        }
        __syncthreads();
        // col-accumulate + store: 8 lanes (cg 0..7) = 128B contiguous per x
        const size_t rowb = ((size_t)(y0 + y + 1) * SP) * CHN;
        #pragma unroll
        for (int m = 0; m < 8; ++m) {
            const int x = x8 + 32 * m;
            float4 a = acc[m];
            a.x += tile[buf][4 * cg + 0][x];
            a.y += tile[buf][4 * cg + 1][x];
            a.z += tile[buf][4 * cg + 2][x];
            a.w += tile[buf][4 * cg + 3][x];
            acc[m] = a;
            *(float4*)(S + rowb + (size_t)(x + 1) * CHN + c0 + 4 * cg) = a;
        }
        if (t < 8)                       // x=0 border for this row
            *(float4*)(S + rowb + c0 + 4 * t) = z4;
        #pragma unroll
        for (int j = 0; j < 8; ++j) cur[j] = nxt[j];
        // no second barrier: next y writes the other LDS buffer; y+2's reuse
        // of this buffer is ordered by the y+1 barrier.
    }
}

// ---------------- offsetK: fp64 prefix of chunk totals ---------------------
// OP[k][x][c], k=0..32; OP[0]=OP[1]=0; OP[k>=2] = sum of chunk totals 0..k-2.
// Chunk j total = S[y=8(j+1)][x][c] (last local row of chunk j).
__global__ __launch_bounds__(256) void offsetK(const float* __restrict__ S,
                                               float* __restrict__ OP) {
    const int gid = blockIdx.x * 256 + threadIdx.x;   // 0 .. 131583 exactly
    const int c = gid & 511, x = gid >> 9;            // x 0..256
    OP[((size_t)0 * SP + x) * CHN + c] = 0.0f;
    OP[((size_t)1 * SP + x) * CHN + c] = 0.0f;
    double run = 0.0;
    for (int j = 0; j < NK - 1; ++j) {
        run += (double)S[((size_t)(YC * (j + 1)) * SP + x) * CHN + c];
        OP[((size_t)(j + 2) * SP + x) * CHN + c] = (float)run;
    }
}

// ---------------- gatherK: per-ROI 9-corner gather with offset add ---------
__global__ __launch_bounds__(256) void gatherK(const float* __restrict__ S,
                                              const float* __restrict__ OP,
                                              const float* __restrict__ roi,
                                              float* __restrict__ out,
                                              float* __restrict__ maskOut,
                                              int N) {
    const int n = blockIdx.x;
    const float xmin = roi[4 * n + 0];
    const float ymin = roi[4 * n + 1];
    const float xmax = roi[4 * n + 2];
    const float ymax = roi[4 * n + 3];

    // Replicate np fp32 op order exactly (no fma contraction).
    const float wsv = __fdiv_rn(__fsub_rn(xmax, xmin), 2.0f);
    const float hsv = __fdiv_rn(__fsub_rn(ymax, ymin), 2.0f);
    const float ax1 = __fadd_rn(xmin, wsv);
    const float ay1 = __fadd_rn(ymin, hsv);
    const float lim = (float)(WD - 1);

    int rx[3], ry[3];
    rx[0] = (int)fminf(fmaxf(rintf(xmin), 0.0f), lim);
    rx[1] = (int)fminf(fmaxf(rintf(ax1), 0.0f), lim);
    rx[2] = (int)fminf(fmaxf(rintf(__fadd_rn(ax1, wsv)), 0.0f), lim);
    ry[0] = (int)fminf(fmaxf(rintf(ymin), 0.0f), lim);
    ry[1] = (int)fminf(fmaxf(rintf(ay1), 0.0f), lim);
    ry[2] = (int)fminf(fmaxf(rintf(__fadd_rn(ay1, hsv)), 0.0f), lim);

    const int t = threadIdx.x;            // c-pair: channels 2t, 2t+1
    float2 g[3][3];
    #pragma unroll
    for (int j = 0; j < 3; ++j) {
        const int kk = (ry[j] + YC - 1) >> 3;   // chunk-offset row in OP
        #pragma unroll
        for (int i = 0; i < 3; ++i) {
            const float2 l = *(const float2*)(S  + ((size_t)ry[j] * SP + rx[i]) * CHN + 2 * t);
            const float2 o = *(const float2*)(OP + ((size_t)kk   * SP + rx[i]) * CHN + 2 * t);
            g[j][i] = make_float2(l.x + o.x, l.y + o.y);
        }
    }

    float m[4];
    #pragma unroll
    for (int p = 0; p < 4; ++p) {
        const int ix = p & 1, iy = p >> 1;
        const int cw = rx[ix + 1] - rx[ix];
        const int ch = ry[iy + 1] - ry[iy];
        const int maskv = (cw >= 1 && ch >= 1) ? 1 : 0;
        int areai = cw * ch; if (areai < 1) areai = 1;
        const float areaf = (float)areai;
        const float maskf = (float)maskv;
        m[p] = maskf;

        const float2 s11 = g[iy + 1][ix + 1];
        const float2 s01 = g[iy][ix + 1];
        const float2 s10 = g[iy + 1][ix];
        const float2 s00 = g[iy][ix];
        float2 o;  // reference order: ((S11 - S01) - S10) + S00, /area, *mask
        o.x = __fdiv_rn(((s11.x - s01.x) - s10.x) + s00.x, areaf) * maskf;
        o.y = __fdiv_rn(((s11.y - s01.y) - s10.y) + s00.y, areaf) * maskf;
        *(float2*)(out + ((size_t)p * N + n) * CHN + 2 * t) = o;
    }
    if (t < 4) maskOut[(size_t)t * N + n] = m[t];
}

// ---------------------------------------------------------------------------
extern "C" void kernel_launch(void* const* d_in, const int* in_sizes, int n_in,
                              void* d_out, int out_size, void* d_ws, size_t ws_size,
                              hipStream_t stream) {
    const float* fm  = (const float*)d_in[0];
    const float* roi = (const float*)d_in[1];
    // d_in[2] = patch_num (always 4 here); pe=2 hardcoded.

    const int N = in_sizes[1] / 4;     // 4096
    const int B = 4 * N;               // 16384

    float* S  = (float*)d_ws;
    float* OP = (float*)d_ws + OP_OFF;
    float* out     = (float*)d_out;
    float* maskOut = out + (size_t)B * CHN;

    dim3 gF(CHN / 32, NK);             // 16 x 32 = 512 blocks
    fusedScanK<<<gF, 256, 0, stream>>>(fm, S);

    offsetK<<<(SP * CHN) / 256, 256, 0, stream>>>(S, OP);   // 514 blocks

    gatherK<<<N, 256, 0, stream>>>(S, OP, roi, out, maskOut, N);
}